// Round 7
// baseline (135.461 us; speedup 1.0000x reference)
//
#include <hip/hip_runtime.h>
#include <math.h>
#include <stdint.h>

#define B_ 4
#define N_ 512
#define D_ 64
#define NDIAG (2 * N_ - 1)   // 1023 diagonal rows of D
#define WV 4                 // waves per block
#define K_ 16                // diagonals per chunk (between barriers)
#define DC0 9                // chunk stagger between adjacent waves
#define NCH 40               // chunks per wave
#define CTOT (DC0 * (WV - 1) + NCH)  // 67
#define RING 1028            // non-wrapping ring: one slot per diagonal
#define BIGF 1e30f           // finite border sentinel: BIG + d rounds to BIG

// Phase 1: D[b][i][j] = ||x[b,i,:]-y[b,j,:]||, stored diagonal-major
__global__ __launch_bounds__(256) void dist_diag_kernel(
    const float* __restrict__ x, const float* __restrict__ y,
    float* __restrict__ ddiag)
{
    const int b = blockIdx.z;
    const int i0 = blockIdx.y * 16;
    const int j0 = blockIdx.x * 16;
    __shared__ float xs[16 * 68];
    __shared__ float ys[16 * 68];
    const int t = threadIdx.x;
    const int lr = t >> 4;
    const int lc = t & 15;
    const float4* xsrc = (const float4*)(x + (((size_t)b * N_) + i0 + lr) * D_);
    const float4* ysrc = (const float4*)(y + (((size_t)b * N_) + j0 + lr) * D_);
    *(float4*)(&xs[lr * 68 + lc * 4]) = xsrc[lc];
    *(float4*)(&ys[lr * 68 + lc * 4]) = ysrc[lc];
    __syncthreads();

    const int ti = t >> 4, tj = t & 15;
    const float* xr = &xs[ti * 68];
    const float* yr = &ys[tj * 68];
    float acc = 0.f;
#pragma unroll
    for (int k = 0; k < 16; ++k) {
        float4 a = *(const float4*)(xr + 4 * k);
        float4 c = *(const float4*)(yr + 4 * k);
        float d0 = a.x - c.x, d1 = a.y - c.y, d2 = a.z - c.z, d3 = a.w - c.w;
        acc += d0 * d0 + d1 * d1 + d2 * d2 + d3 * d3;
    }
    const int i = i0 + ti, j = j0 + tj;
    ddiag[((size_t)b * NDIAG + (size_t)(i + j)) * N_ + j] = sqrtf(acc);
}

__device__ __forceinline__ float dpp_shr1(float x) {
    int v = __builtin_amdgcn_update_dpp(0x7f800000, __float_as_int(x),
                                        0x138 /*WAVE_SHR1*/, 0xf, 0xf, false);
    return __int_as_float(v);
}

__device__ __forceinline__ float vmin3(float a, float b, float c) {
    float r; asm("v_min3_f32 %0, %1, %2, %3" : "=v"(r) : "v"(a), "v"(b), "v"(c)); return r;
}
__device__ __forceinline__ float vmed3(float a, float b, float c) {
    float r; asm("v_med3_f32 %0, %1, %2, %3" : "=v"(r) : "v"(a), "v"(b), "v"(c)); return r;
}
__device__ __forceinline__ float vmax3(float a, float b, float c) {
    float r; asm("v_max3_f32 %0, %1, %2, %3" : "=v"(r) : "v"(a), "v"(b), "v"(c)); return r;
}

#if __has_builtin(__builtin_amdgcn_exp2f)
#define EXP2(x) __builtin_amdgcn_exp2f(x)
#else
#define EXP2(x) exp2f(x)
#endif
#if __has_builtin(__builtin_amdgcn_logf)
#define LOG2(x) __builtin_amdgcn_logf(x)
#else
#define LOG2(x) log2f(x)
#endif

// Phase 2: staggered register-resident soft-DTW, TRUE register d-transport.
// R6 post-mortem: VGPR_Count=68 proved the 64-VGPR d-queue was spilled to
// scratch (compiler occupancy heuristic) -> every consumption = scratch load
// on the serial chain. Fix: __launch_bounds__(256,1) lifts VGPR budget to
// ~512; 3-buffer queue, 2-chunk-ahead prefetch, exact counted vmcnt waits.
// All queue indices compile-time (rule #20) via switch(lc%3) with literals.
__global__ __launch_bounds__(256, 1) void sdtw_reg2_kernel(
    const float* __restrict__ ddiag, float* __restrict__ out)
{
    const int b = blockIdx.x;
    const int tid = threadIdx.x;
    const int w = tid >> 6;
    const int lane = tid & 63;
    const float* Db = ddiag + (size_t)b * (NDIAG * (size_t)N_);

    // deterministic monotone paths: arange(512) for both
    for (int q = tid; q < N_; q += 256) {
        out[b * N_ + q] = (float)q;
        out[B_ * N_ + b * N_ + q] = (float)q;
    }

    __shared__ __align__(16) float ring[WV + 1][RING];
    for (int q = tid; q < (WV + 1) * RING; q += 256)
        (&ring[0][0])[q] = (q == 0) ? 0.0f : BIGF;
    // drain the path stores so vmcnt counts only our asm loads below
    asm volatile("s_waitcnt vmcnt(0)");
    __syncthreads();

    const float C1 = 14.4269504089f;    // (1/gamma)*log2(e)
    const float C2 = -0.069314718056f;  // -gamma*ln(2)
    const int c0w = DC0 * w;
    const int s0w = 128 * w + 2;
    const bool l0 = (lane == 0);
    const bool l63 = (lane == 63);
    const float* ringR = ring[w];
    float* ringW = ring[w + 1];
    const uint64_t dlane = (uint64_t)(Db + 128 * w + 2 * lane);

    unsigned u0 = (unsigned)(-(2 * lane));
    float rA0 = BIGF, rB0 = BIGF, rA1 = BIGF;
    float lnL = BIGF, ldL = BIGF;
    float res = 0.0f;

    float2 vq[3 * K_];  // 96-VGPR register d-queue; all indices literal

// issue chunk lcn_'s 16 row-loads into queue buffer buf_ (literal 0/1/2)
#define ISSUE16(lcn_, buf_)                                                 \
    {                                                                       \
        const int s0n_ = s0w + (lcn_) * K_;                                 \
        _Pragma("unroll")                                                   \
        for (int t = 0; t < K_; ++t) {                                      \
            int rown_ = s0n_ - 2 + t;                                       \
            rown_ = rown_ > (NDIAG - 1) ? (NDIAG - 1) : rown_;              \
            uint64_t a_ = dlane + (uint64_t)rown_ * (uint64_t)(N_ * 4);     \
            asm volatile("global_load_dwordx2 %0, %1, off"                  \
                         : "=v"(vq[(buf_) * K_ + t]) : "v"(a_));            \
        }                                                                   \
    }

#define TIE8(o_, p_)                                                        \
    asm volatile("" : "+v"(vq[(o_) + (p_) + 0]), "+v"(vq[(o_) + (p_) + 1]), \
                      "+v"(vq[(o_) + (p_) + 2]), "+v"(vq[(o_) + (p_) + 3]), \
                      "+v"(vq[(o_) + (p_) + 4]), "+v"(vq[(o_) + (p_) + 5]), \
                      "+v"(vq[(o_) + (p_) + 6]), "+v"(vq[(o_) + (p_) + 7]))

// consume buffer par_, issue chunk lc+2 into buffer (par_+2)%3.
// waits are EXACT: steady state 48 outstanding -> vmcnt(32) = chunk lc landed
#define CHUNK(par_)                                                         \
    {                                                                       \
        const int s0c = s0w + lc * K_;                                      \
        constexpr int o_ = (par_) * K_;                                     \
        if (lc + 2 < NCH) {                                                 \
            ISSUE16(lc + 2, ((par_) + 2) % 3);                              \
            asm volatile("s_waitcnt vmcnt(32)");                            \
        } else if (lc + 1 < NCH) {                                          \
            asm volatile("s_waitcnt vmcnt(16)");                            \
        } else {                                                            \
            asm volatile("s_waitcnt vmcnt(0)");                             \
        }                                                                   \
        TIE8(o_, 0); TIE8(o_, 8); /* order uses after the wait (r#18) */    \
        float rr[18];                                                       \
        {                                                                   \
            const float4 q0 = *(const float4*)&ringR[s0c - 2];              \
            const float4 q1 = *(const float4*)&ringR[s0c + 2];              \
            const float4 q2 = *(const float4*)&ringR[s0c + 6];              \
            const float4 q3 = *(const float4*)&ringR[s0c + 10];             \
            const float2 q4 = *(const float2*)&ringR[s0c + 14];             \
            rr[0] = q0.x; rr[1] = q0.y; rr[2] = q0.z; rr[3] = q0.w;         \
            rr[4] = q1.x; rr[5] = q1.y; rr[6] = q1.z; rr[7] = q1.w;         \
            rr[8] = q2.x; rr[9] = q2.y; rr[10] = q2.z; rr[11] = q2.w;       \
            rr[12] = q3.x; rr[13] = q3.y; rr[14] = q3.z; rr[15] = q3.w;     \
            rr[16] = q4.x; rr[17] = q4.y;                                   \
        }                                                                   \
        if (lc == 0) {                                                      \
            lnL = l0 ? rr[1] : BIGF;                                        \
            ldL = l0 ? rr[0] : BIGF;                                        \
        }                                                                   \
        _Pragma("unroll")                                                   \
        for (int t = 0; t < K_; ++t) {                                      \
            const float d0 = vq[o_ + t].x, d1 = vq[o_ + t].y;               \
            float m0  = vmin3(rA0, lnL, ldL);                               \
            float md0 = vmed3(rA0, lnL, ldL);                               \
            float mx0 = vmax3(rA0, lnL, ldL);                               \
            float e0 = EXP2((m0 - md0) * C1);                               \
            float f0 = EXP2((m0 - mx0) * C1);                               \
            float r0 = fmaf(C2, LOG2(1.0f + e0 + f0), m0 + d0);             \
            float m1  = vmin3(rA1, rA0, rB0);                               \
            float md1 = vmed3(rA1, rA0, rB0);                               \
            float mx1 = vmax3(rA1, rA0, rB0);                               \
            float e1 = EXP2((m1 - md1) * C1);                               \
            float f1 = EXP2((m1 - mx1) * C1);                               \
            float r1 = fmaf(C2, LOG2(1.0f + e1 + f1), m1 + d1);             \
            res = (u0 == 512u) ? r1 : res;                                  \
            u0 += 1u;                                                       \
            rB0 = rA0; rA0 = r0;                                            \
            ldL = lnL;                                                      \
            float sh = dpp_shr1(r1);                                        \
            lnL = l0 ? rr[t + 2] : sh;                                      \
            rA1 = r1;                                                       \
            if (l63) ringW[s0c + t] = r1;                                   \
        }                                                                   \
    }

    if (w == 0) { ISSUE16(0, 0); ISSUE16(1, 1); }  // wave-0 prologue

    for (int c = 0; c < CTOT; ++c) {
        const int lc = c - c0w;
        if (lc >= 0 && lc < NCH) {
            switch (lc % 3) {
                case 0: { CHUNK(0) } break;
                case 1: { CHUNK(1) } break;
                default: { CHUNK(2) } break;
            }
        } else if (lc == -2) {
            ISSUE16(0, 0);
        } else if (lc == -1) {
            ISSUE16(1, 1);
        }
        // LDS-only drain + barrier (register d-loads stay in flight)
        asm volatile("s_waitcnt lgkmcnt(0)" ::: "memory");
        __builtin_amdgcn_s_barrier();
    }
#undef CHUNK
#undef TIE8
#undef ISSUE16

    // R[512][512] captured by wave 3 / lane 63 at i1 == 512
    if (w == WV - 1 && l63) out[2 * B_ * N_ + b] = res;
}

extern "C" void kernel_launch(void* const* d_in, const int* in_sizes, int n_in,
                              void* d_out, int out_size, void* d_ws, size_t ws_size,
                              hipStream_t stream) {
    const float* x = (const float*)d_in[0];
    const float* y = (const float*)d_in[1];
    float* out = (float*)d_out;
    float* ddiag = (float*)d_ws;  // 4*1023*512*4 B = 8.0 MB

    dim3 g1(N_ / 16, N_ / 16, B_);
    dist_diag_kernel<<<g1, 256, 0, stream>>>(x, y, ddiag);
    sdtw_reg2_kernel<<<B_, 256, 0, stream>>>(ddiag, out);
}

// Round 8
// 133.893 us; speedup vs baseline: 1.0117x; 1.0117x over previous
//
#include <hip/hip_runtime.h>
#include <math.h>
#include <stdint.h>

#define B_ 4
#define N_ 512
#define D_ 64
#define NDIAG (2 * N_ - 1)   // 1023 diagonal rows of D
#define WV 4                 // waves per block
#define K_ 16                // diagonals per chunk (between barriers)
#define DC0 9                // chunk stagger between adjacent waves
#define NCH 40               // chunks per wave
#define CTOT (DC0 * (WV - 1) + NCH)  // 67
#define RING 1028            // non-wrapping ring: one slot per diagonal
#define BIGF 1e30f           // finite border sentinel: BIG + d rounds to BIG

// Phase 1: D[b][i][j] = ||x[b,i,:]-y[b,j,:]||, stored diagonal-major
__global__ __launch_bounds__(256) void dist_diag_kernel(
    const float* __restrict__ x, const float* __restrict__ y,
    float* __restrict__ ddiag)
{
    const int b = blockIdx.z;
    const int i0 = blockIdx.y * 16;
    const int j0 = blockIdx.x * 16;
    __shared__ float xs[16 * 68];
    __shared__ float ys[16 * 68];
    const int t = threadIdx.x;
    const int lr = t >> 4;
    const int lc = t & 15;
    const float4* xsrc = (const float4*)(x + (((size_t)b * N_) + i0 + lr) * D_);
    const float4* ysrc = (const float4*)(y + (((size_t)b * N_) + j0 + lr) * D_);
    *(float4*)(&xs[lr * 68 + lc * 4]) = xsrc[lc];
    *(float4*)(&ys[lr * 68 + lc * 4]) = ysrc[lc];
    __syncthreads();

    const int ti = t >> 4, tj = t & 15;
    const float* xr = &xs[ti * 68];
    const float* yr = &ys[tj * 68];
    float acc = 0.f;
#pragma unroll
    for (int k = 0; k < 16; ++k) {
        float4 a = *(const float4*)(xr + 4 * k);
        float4 c = *(const float4*)(yr + 4 * k);
        float d0 = a.x - c.x, d1 = a.y - c.y, d2 = a.z - c.z, d3 = a.w - c.w;
        acc += d0 * d0 + d1 * d1 + d2 * d2 + d3 * d3;
    }
    const int i = i0 + ti, j = j0 + tj;
    ddiag[((size_t)b * NDIAG + (size_t)(i + j)) * N_ + j] = sqrtf(acc);
}

__device__ __forceinline__ float dpp_shr1(float x) {
    int v = __builtin_amdgcn_update_dpp(0x7f800000, __float_as_int(x),
                                        0x138 /*WAVE_SHR1*/, 0xf, 0xf, false);
    return __int_as_float(v);
}

__device__ __forceinline__ float vmin3(float a, float b, float c) {
    float r; asm("v_min3_f32 %0, %1, %2, %3" : "=v"(r) : "v"(a), "v"(b), "v"(c)); return r;
}
__device__ __forceinline__ float vmed3(float a, float b, float c) {
    float r; asm("v_med3_f32 %0, %1, %2, %3" : "=v"(r) : "v"(a), "v"(b), "v"(c)); return r;
}
__device__ __forceinline__ float vmax3(float a, float b, float c) {
    float r; asm("v_max3_f32 %0, %1, %2, %3" : "=v"(r) : "v"(a), "v"(b), "v"(c)); return r;
}

#if __has_builtin(__builtin_amdgcn_exp2f)
#define EXP2(x) __builtin_amdgcn_exp2f(x)
#else
#define EXP2(x) exp2f(x)
#endif
#if __has_builtin(__builtin_amdgcn_logf)
#define LOG2(x) __builtin_amdgcn_logf(x)
#else
#define LOG2(x) log2f(x)
#endif

// Phase 2: staggered soft-DTW, register d-queue as 48 NAMED float2 scalars.
// R7 post-mortem: float2 vq[48] is an alloca; SROA runs before unrolling so
// asm outputs with loop-variant indices pin the queue in SCRATCH (VGPR=100
// proved it). Named scalars cannot be allocas -> asm outputs are real VGPRs.
__global__ __launch_bounds__(256, 1) void sdtw_reg3_kernel(
    const float* __restrict__ ddiag, float* __restrict__ out)
{
    const int b = blockIdx.x;
    const int tid = threadIdx.x;
    const int w = tid >> 6;
    const int lane = tid & 63;
    const float* Db = ddiag + (size_t)b * (NDIAG * (size_t)N_);

    // deterministic monotone paths: arange(512) for both
    for (int q = tid; q < N_; q += 256) {
        out[b * N_ + q] = (float)q;
        out[B_ * N_ + b * N_ + q] = (float)q;
    }

    __shared__ __align__(16) float ring[WV + 1][RING];
    for (int q = tid; q < (WV + 1) * RING; q += 256)
        (&ring[0][0])[q] = (q == 0) ? 0.0f : BIGF;
    // drain path stores so vmcnt counts only our asm loads below
    asm volatile("s_waitcnt vmcnt(0)");
    __syncthreads();

    const float C1 = 14.4269504089f;    // (1/gamma)*log2(e)
    const float C2 = -0.069314718056f;  // -gamma*ln(2)
    const int c0w = DC0 * w;
    const int s0w = 128 * w + 2;
    const bool l0 = (lane == 0);
    const bool l63 = (lane == 63);
    const float* ringR = ring[w];
    float* ringW = ring[w + 1];
    const uint64_t dlane = (uint64_t)(Db + 128 * w + 2 * lane);

    unsigned u0 = (unsigned)(-(2 * lane));
    float rA0 = BIGF, rB0 = BIGF, rA1 = BIGF;
    float lnL = BIGF, ldL = BIGF;
    float res = 0.0f;

    // 48 named float2 scalars: 3 buffers x 16 rows (96 VGPRs when live)
#define DECLQ(b_)                                                           \
    float2 q##b_##_0 = {0, 0}, q##b_##_1 = {0, 0}, q##b_##_2 = {0, 0},      \
           q##b_##_3 = {0, 0}, q##b_##_4 = {0, 0}, q##b_##_5 = {0, 0},      \
           q##b_##_6 = {0, 0}, q##b_##_7 = {0, 0}, q##b_##_8 = {0, 0},      \
           q##b_##_9 = {0, 0}, q##b_##_10 = {0, 0}, q##b_##_11 = {0, 0},    \
           q##b_##_12 = {0, 0}, q##b_##_13 = {0, 0}, q##b_##_14 = {0, 0},   \
           q##b_##_15 = {0, 0};
    DECLQ(0) DECLQ(1) DECLQ(2)

#define LOADQ(qv_, rown_)                                                   \
    {                                                                       \
        const int rq_ = (rown_) > (NDIAG - 1) ? (NDIAG - 1) : (rown_);      \
        const uint64_t a_ = dlane + (uint64_t)rq_ * (uint64_t)(N_ * 4);     \
        asm volatile("global_load_dwordx2 %0, %1, off"                      \
                     : "=v"(qv_) : "v"(a_));                                \
    }

#define ISSUE16(lcn_, b_)                                                   \
    {                                                                       \
        const int s0n_ = s0w + (lcn_) * K_;                                 \
        LOADQ(q##b_##_0,  s0n_ - 2)  LOADQ(q##b_##_1,  s0n_ - 1)            \
        LOADQ(q##b_##_2,  s0n_ + 0)  LOADQ(q##b_##_3,  s0n_ + 1)            \
        LOADQ(q##b_##_4,  s0n_ + 2)  LOADQ(q##b_##_5,  s0n_ + 3)            \
        LOADQ(q##b_##_6,  s0n_ + 4)  LOADQ(q##b_##_7,  s0n_ + 5)            \
        LOADQ(q##b_##_8,  s0n_ + 6)  LOADQ(q##b_##_9,  s0n_ + 7)            \
        LOADQ(q##b_##_10, s0n_ + 8)  LOADQ(q##b_##_11, s0n_ + 9)            \
        LOADQ(q##b_##_12, s0n_ + 10) LOADQ(q##b_##_13, s0n_ + 11)           \
        LOADQ(q##b_##_14, s0n_ + 12) LOADQ(q##b_##_15, s0n_ + 13)           \
    }

// tie uses after the vmcnt wait (rule #18): re-define all 16 names
#define TIEB(b_)                                                            \
    asm volatile("" : "+v"(q##b_##_0), "+v"(q##b_##_1), "+v"(q##b_##_2),    \
                      "+v"(q##b_##_3), "+v"(q##b_##_4), "+v"(q##b_##_5),    \
                      "+v"(q##b_##_6), "+v"(q##b_##_7));                    \
    asm volatile("" : "+v"(q##b_##_8), "+v"(q##b_##_9), "+v"(q##b_##_10),   \
                      "+v"(q##b_##_11), "+v"(q##b_##_12), "+v"(q##b_##_13), \
                      "+v"(q##b_##_14), "+v"(q##b_##_15));

#define STEP(dq_, tt_, rrn_)                                                \
    {                                                                       \
        const float d0 = dq_.x, d1 = dq_.y;                                 \
        float m0  = vmin3(rA0, lnL, ldL);                                   \
        float md0 = vmed3(rA0, lnL, ldL);                                   \
        float mx0 = vmax3(rA0, lnL, ldL);                                   \
        float e0 = EXP2((m0 - md0) * C1);                                   \
        float f0 = EXP2((m0 - mx0) * C1);                                   \
        float r0 = fmaf(C2, LOG2(1.0f + e0 + f0), m0 + d0);                 \
        float m1  = vmin3(rA1, rA0, rB0);                                   \
        float md1 = vmed3(rA1, rA0, rB0);                                   \
        float mx1 = vmax3(rA1, rA0, rB0);                                   \
        float e1 = EXP2((m1 - md1) * C1);                                   \
        float f1 = EXP2((m1 - mx1) * C1);                                   \
        float r1 = fmaf(C2, LOG2(1.0f + e1 + f1), m1 + d1);                 \
        res = (u0 == 512u) ? r1 : res;                                      \
        u0 += 1u;                                                           \
        rB0 = rA0; rA0 = r0;                                                \
        ldL = lnL;                                                          \
        float sh = dpp_shr1(r1);                                            \
        lnL = l0 ? (rrn_) : sh;                                             \
        rA1 = r1;                                                           \
        if (l63) ringW[s0c + (tt_)] = r1;                                   \
    }

// consume buffer b_, issue chunk lc+2 into buffer b2_ = (b_+2)%3.
// exact counted waits: steady 48 outstanding -> vmcnt(32) = chunk lc landed
#define CHUNK(b_, b2_)                                                      \
    {                                                                       \
        const int s0c = s0w + lc * K_;                                      \
        if (lc + 2 < NCH) {                                                 \
            ISSUE16(lc + 2, b2_);                                           \
            asm volatile("s_waitcnt vmcnt(32)");                            \
        } else if (lc + 1 < NCH) {                                          \
            asm volatile("s_waitcnt vmcnt(16)");                            \
        } else {                                                            \
            asm volatile("s_waitcnt vmcnt(0)");                             \
        }                                                                   \
        TIEB(b_);                                                           \
        const float4 qr0 = *(const float4*)&ringR[s0c - 2];                 \
        const float4 qr1 = *(const float4*)&ringR[s0c + 2];                 \
        const float4 qr2 = *(const float4*)&ringR[s0c + 6];                 \
        const float4 qr3 = *(const float4*)&ringR[s0c + 10];                \
        const float2 qr4 = *(const float2*)&ringR[s0c + 14];                \
        const float rr0 = qr0.x, rr1 = qr0.y, rr2 = qr0.z, rr3 = qr0.w;     \
        const float rr4 = qr1.x, rr5 = qr1.y, rr6 = qr1.z, rr7 = qr1.w;     \
        const float rr8 = qr2.x, rr9 = qr2.y, rr10 = qr2.z, rr11 = qr2.w;   \
        const float rr12 = qr3.x, rr13 = qr3.y, rr14 = qr3.z, rr15 = qr3.w; \
        const float rr16 = qr4.x, rr17 = qr4.y;                             \
        if (lc == 0) {                                                      \
            lnL = l0 ? rr1 : BIGF;                                          \
            ldL = l0 ? rr0 : BIGF;                                          \
        }                                                                   \
        STEP(q##b_##_0, 0, rr2)   STEP(q##b_##_1, 1, rr3)                   \
        STEP(q##b_##_2, 2, rr4)   STEP(q##b_##_3, 3, rr5)                   \
        STEP(q##b_##_4, 4, rr6)   STEP(q##b_##_5, 5, rr7)                   \
        STEP(q##b_##_6, 6, rr8)   STEP(q##b_##_7, 7, rr9)                   \
        STEP(q##b_##_8, 8, rr10)  STEP(q##b_##_9, 9, rr11)                  \
        STEP(q##b_##_10, 10, rr12) STEP(q##b_##_11, 11, rr13)               \
        STEP(q##b_##_12, 12, rr14) STEP(q##b_##_13, 13, rr15)               \
        STEP(q##b_##_14, 14, rr16) STEP(q##b_##_15, 15, rr17)               \
    }

    if (w == 0) { ISSUE16(0, 0); ISSUE16(1, 1); }  // wave-0 prologue

    for (int c = 0; c < CTOT; ++c) {
        const int lc = c - c0w;
        if (lc >= 0 && lc < NCH) {
            switch (lc % 3) {
                case 0: { CHUNK(0, 2) } break;
                case 1: { CHUNK(1, 0) } break;
                default: { CHUNK(2, 1) } break;
            }
        } else if (lc == -2) {
            ISSUE16(0, 0);
        } else if (lc == -1) {
            ISSUE16(1, 1);
        }
        // LDS-only drain + barrier (register d-loads stay in flight)
        asm volatile("s_waitcnt lgkmcnt(0)" ::: "memory");
        __builtin_amdgcn_s_barrier();
    }
#undef CHUNK
#undef STEP
#undef TIEB
#undef ISSUE16
#undef LOADQ
#undef DECLQ

    // R[512][512] captured by wave 3 / lane 63 at i1 == 512
    if (w == WV - 1 && l63) out[2 * B_ * N_ + b] = res;
}

extern "C" void kernel_launch(void* const* d_in, const int* in_sizes, int n_in,
                              void* d_out, int out_size, void* d_ws, size_t ws_size,
                              hipStream_t stream) {
    const float* x = (const float*)d_in[0];
    const float* y = (const float*)d_in[1];
    float* out = (float*)d_out;
    float* ddiag = (float*)d_ws;  // 4*1023*512*4 B = 8.0 MB

    dim3 g1(N_ / 16, N_ / 16, B_);
    dist_diag_kernel<<<g1, 256, 0, stream>>>(x, y, ddiag);
    sdtw_reg3_kernel<<<B_, 256, 0, stream>>>(ddiag, out);
}